// Round 1
// baseline (117.172 us; speedup 1.0000x reference)
//
#include <hip/hip_runtime.h>
#include <hip/hip_bf16.h>
#include <stdint.h>

// Problem constants (from reference)
#define BB 16
#define NN 64
#define DEG 16
#define IN_F 1024
#define EDGE_F 128
#define OUT_FT 512
#define HH 8
#define FF 64
#define EE (NN*DEG)       // 1024
#define SLOPE 0.2f

typedef short s16x8 __attribute__((ext_vector_type(8)));
typedef float f32x4 __attribute__((ext_vector_type(4)));

__device__ __forceinline__ unsigned short f2bf(float x) {
    union { float f; uint32_t u; } v; v.f = x;
    uint32_t u = v.u;
    return (unsigned short)((u + 0x7FFFu + ((u >> 16) & 1u)) >> 16);  // RNE
}

// ---------------------------------------------------------------------------
// prep: blocks 0..127  : transpose+convert W_node[1024][512] -> W_T bf16 [512][1024]
//       block 128      : wv[c][h] = sum_f W_edge[c][h*64+f] * w_attn[128+f]
//       blocks 129..144: row_start[b][i] = exclusive count of nonzeros in rows < i
// ---------------------------------------------------------------------------
__global__ __launch_bounds__(256)
void prep_kernel(const float* __restrict__ W_node,
                 const float* __restrict__ W_edge,
                 const float* __restrict__ w_attn,
                 const float* __restrict__ adj,
                 unsigned short* __restrict__ W_T,
                 float* __restrict__ wv,
                 int* __restrict__ row_start)
{
    int bx = blockIdx.x;
    int tid = threadIdx.x;

    if (bx < 128) {
        // transpose role: tile (tk,tn), 64x64
        __shared__ float tile[64][65];
        int tn = bx & 7;         // n tile 0..7
        int tk = bx >> 3;        // k tile 0..15
        int k0 = tk * 64, n0 = tn * 64;
        #pragma unroll
        for (int j = 0; j < 16; ++j) {
            int lin = j * 256 + tid;
            int r = lin >> 6, c = lin & 63;
            tile[r][c] = W_node[(size_t)(k0 + r) * 512 + n0 + c];
        }
        __syncthreads();
        #pragma unroll
        for (int j = 0; j < 16; ++j) {
            int lin = j * 256 + tid;
            int nr = lin >> 6, kc = lin & 63;
            W_T[(size_t)(n0 + nr) * 1024 + k0 + kc] = f2bf(tile[kc][nr]);
        }
    } else if (bx == 128) {
        // wv role
        int c = tid & 127;
        int half = tid >> 7;     // 0..1
        const float* we = w_attn + 2 * FF;   // w_e
        #pragma unroll
        for (int hh = 0; hh < 4; ++hh) {
            int h = half * 4 + hh;
            float s = 0.f;
            const float* row = W_edge + (size_t)c * 512 + h * 64;
            #pragma unroll 8
            for (int f = 0; f < 64; ++f) s += row[f] * we[f];
            wv[c * 8 + h] = s;
        }
    } else {
        // row_start role
        int b = bx - 129;
        if (tid < 64) {
            const float* row = adj + (size_t)b * 4096 + (size_t)tid * 64;
            int cnt = 0;
            #pragma unroll 8
            for (int j = 0; j < 64; ++j) cnt += (row[j] > 0.5f) ? 1 : 0;
            int inc = cnt;
            #pragma unroll
            for (int d = 1; d < 64; d <<= 1) {
                int u = __shfl_up(inc, d, 64);
                if (tid >= d) inc += u;
            }
            row_start[b * 64 + tid] = inc - cnt;   // exclusive
        }
    }
}

// ---------------------------------------------------------------------------
// GEMM: g[1024][512] = h[1024][1024] @ W_node  (via bf16 MFMA, W_T pre-transposed)
// 64x64 tile, BK=32, 256 threads (4 waves), wave w -> rows [16w,16w+16), 4 n-tiles
// ---------------------------------------------------------------------------
__global__ __launch_bounds__(256)
void gemm_g_kernel(const float* __restrict__ hmat,          // [1024][1024]
                   const unsigned short* __restrict__ W_T,  // [512][1024] bf16
                   float* __restrict__ g)                   // [1024][512]
{
    __shared__ __align__(16) unsigned short As[64][40];   // +8 pad
    __shared__ __align__(16) unsigned short Bs[64][40];

    int tid  = threadIdx.x;
    int m0   = blockIdx.y * 64;
    int n0   = blockIdx.x * 64;
    int wave = tid >> 6;
    int lane = tid & 63;
    int l15  = lane & 15;
    int quad = lane >> 4;
    int wv16 = wave * 16;

    int ldr  = tid >> 2;          // 0..63
    int ldc8 = (tid & 3) * 8;     // 0,8,16,24

    f32x4 acc[4];
    #pragma unroll
    for (int i = 0; i < 4; ++i) acc[i] = (f32x4){0.f, 0.f, 0.f, 0.f};

    for (int k0 = 0; k0 < 1024; k0 += 32) {
        // stage A: fp32 -> bf16
        const float* ap = hmat + (size_t)(m0 + ldr) * 1024 + k0 + ldc8;
        float4 a0 = *(const float4*)ap;
        float4 a1 = *(const float4*)(ap + 4);
        s16x8 av;
        av[0] = (short)f2bf(a0.x); av[1] = (short)f2bf(a0.y);
        av[2] = (short)f2bf(a0.z); av[3] = (short)f2bf(a0.w);
        av[4] = (short)f2bf(a1.x); av[5] = (short)f2bf(a1.y);
        av[6] = (short)f2bf(a1.z); av[7] = (short)f2bf(a1.w);
        *(s16x8*)&As[ldr][ldc8] = av;
        // stage B: already bf16
        *(int4*)&Bs[ldr][ldc8] =
            *(const int4*)(W_T + (size_t)(n0 + ldr) * 1024 + k0 + ldc8);
        __syncthreads();

        s16x8 af = *(const s16x8*)&As[wv16 + l15][quad * 8];
        #pragma unroll
        for (int nt = 0; nt < 4; ++nt) {
            s16x8 bf = *(const s16x8*)&Bs[nt * 16 + l15][quad * 8];
            acc[nt] = __builtin_amdgcn_mfma_f32_16x16x32_bf16(af, bf, acc[nt], 0, 0, 0);
        }
        __syncthreads();
    }

    #pragma unroll
    for (int nt = 0; nt < 4; ++nt) {
        #pragma unroll
        for (int reg = 0; reg < 4; ++reg) {
            int gm = m0 + wv16 + quad * 4 + reg;
            int gn = n0 + nt * 16 + l15;
            g[(size_t)gm * 512 + gn] = acc[nt][reg];
        }
    }
}

// ---------------------------------------------------------------------------
// edge scores: s_e[b][e][h] = edge_attr[b,e,:] . wv[:,h]
// thread per (b,e); 16384 threads
// ---------------------------------------------------------------------------
__global__ __launch_bounds__(256)
void edge_scores_kernel(const float* __restrict__ edge_attr,  // [16*1024][128]
                        const float* __restrict__ wv,         // [128][8]
                        float* __restrict__ s_e)              // [16*1024][8]
{
    __shared__ float wvs[128 * 8];
    int tid = threadIdx.x;
    for (int i = tid; i < 1024; i += 256) wvs[i] = wv[i];
    __syncthreads();

    int idx = blockIdx.x * 256 + tid;     // 0..16383
    const float* row = edge_attr + (size_t)idx * 128;
    float acc[8];
    #pragma unroll
    for (int h = 0; h < 8; ++h) acc[h] = 0.f;

    for (int c = 0; c < 128; c += 4) {
        float4 v = *(const float4*)(row + c);
        const float* w0 = &wvs[(c + 0) * 8];
        #pragma unroll
        for (int h = 0; h < 8; ++h) acc[h] += v.x * w0[h];
        const float* w1 = &wvs[(c + 1) * 8];
        #pragma unroll
        for (int h = 0; h < 8; ++h) acc[h] += v.y * w1[h];
        const float* w2 = &wvs[(c + 2) * 8];
        #pragma unroll
        for (int h = 0; h < 8; ++h) acc[h] += v.z * w2[h];
        const float* w3 = &wvs[(c + 3) * 8];
        #pragma unroll
        for (int h = 0; h < 8; ++h) acc[h] += v.w * w3[h];
    }
    float* o = s_e + (size_t)idx * 8;
    #pragma unroll
    for (int h = 0; h < 8; ++h) o[h] = acc[h];
}

// ---------------------------------------------------------------------------
// attention + aggregation: one block per (b,i)
// ---------------------------------------------------------------------------
__global__ __launch_bounds__(256)
void attn_kernel(const float* __restrict__ g,          // [1024][512]
                 const float* __restrict__ adj,        // [16][64][64]
                 const float* __restrict__ s_e,        // [16*1024][8]
                 const int*   __restrict__ row_start,  // [16][64]
                 const float* __restrict__ w_attn,     // [192]
                 float* __restrict__ out)              // [1024][512]
{
    __shared__ float gs[17][516];      // neighbor rows (<=16) + row i at slot m_nb
    __shared__ float sj[17][8];
    __shared__ float se_s[16][8];
    __shared__ float a_s[16][8];
    __shared__ float wij[128];         // [0..63]=w_i, [64..127]=w_j
    __shared__ int   nbr[64];
    __shared__ int   m_nb_s;

    int bi = blockIdx.x;               // b*64 + i
    int b  = bi >> 6;
    int i  = bi & 63;
    int tid = threadIdx.x;

    // Phase A: neighbor scan (wave 0) + w_i/w_j load (other threads)
    if (tid < 64) {
        float av = adj[(size_t)b * 4096 + (size_t)i * 64 + tid];
        unsigned long long m = __ballot(av > 0.5f);
        if (av > 0.5f) {
            int before = __popcll(m & ((1ull << tid) - 1ull));
            if (before < 16) nbr[before] = tid;
        }
        if (tid == 0) {
            int c = __popcll(m);
            m_nb_s = (c > 16) ? 16 : c;
        }
    } else if (tid < 192) {
        wij[tid - 64] = w_attn[tid - 64];
    }
    __syncthreads();

    int m_nb = m_nb_s;
    int rs   = row_start[b * 64 + i];

    // Phase B1: stage g rows (neighbors + row i) into LDS; fetch s_e
    for (int r = 0; r <= m_nb; ++r) {
        int src = (r == m_nb) ? i : nbr[r];
        const float* gr = g + (size_t)(b * 64 + src) * 512;
        *(float2*)&gs[r][tid * 2] = *(const float2*)(gr + tid * 2);
    }
    if (tid < 128) {
        int k = tid >> 3, h = tid & 7;
        if (k < m_nb) se_s[k][h] = s_e[(size_t)(b * 1024 + rs + k) * 8 + h];
    }
    __syncthreads();

    // Phase B2: sj[r][h] dots (staggered LDS reads to dodge bank conflicts)
    {
        int r = tid >> 3, h = tid & 7;
        if (r <= m_nb) {
            const float* wsel = (r == m_nb) ? &wij[0] : &wij[64];  // w_i for row i
            const float* grow = &gs[r][h * 64];
            float s = 0.f;
            int base = tid & 63;
            #pragma unroll 8
            for (int ff = 0; ff < 64; ++ff) {
                int f = (ff + base) & 63;
                s += grow[f] * wsel[f];
            }
            sj[r][h] = s;
        }
    }
    __syncthreads();

    // Phase B3: scores + softmax per head (8 lanes)
    if (tid < 8) {
        int h = tid;
        float si = sj[m_nb][h];
        float sc[16];
        float mx = -1e30f;
        for (int k = 0; k < m_nb; ++k) {
            float v = si + sj[k][h] + se_s[k][h];
            v = (v >= 0.f) ? v : SLOPE * v;
            sc[k] = v;
            mx = fmaxf(mx, v);
        }
        float ssum = 0.f;
        for (int k = 0; k < m_nb; ++k) {
            float e = __expf(sc[k] - mx);
            a_s[k][h] = e;
            ssum += e;
        }
        float inv = 1.f / ssum;
        for (int k = 0; k < m_nb; ++k) a_s[k][h] *= inv;
    }
    __syncthreads();

    // Phase B4: aggregate out[h][f] = sum_k a[k][h] * g_nbr[k][h*64+f]
    #pragma unroll
    for (int o = tid; o < 512; o += 256) {
        int h = o >> 6, f = o & 63;
        float s = 0.f;
        for (int k = 0; k < m_nb; ++k) s += a_s[k][h] * gs[k][h * 64 + f];
        out[(size_t)bi * 512 + o] = s;
    }
}

// ---------------------------------------------------------------------------
extern "C" void kernel_launch(void* const* d_in, const int* in_sizes, int n_in,
                              void* d_out, int out_size, void* d_ws, size_t ws_size,
                              hipStream_t stream) {
    const float* h_in      = (const float*)d_in[0];   // (16,64,1024)
    const float* adj_mat   = (const float*)d_in[1];   // (16,64,64)
    const float* edge_attr = (const float*)d_in[2];   // (16,1024,128)
    const float* W_node    = (const float*)d_in[3];   // (1024,512)
    const float* W_edge    = (const float*)d_in[4];   // (128,512)
    const float* w_attn    = (const float*)d_in[5];   // (192,)
    float* out = (float*)d_out;                       // (16,64,512) fp32

    char* ws = (char*)d_ws;
    unsigned short* W_T = (unsigned short*)ws;                 // 1 MB
    float* g            = (float*)(ws + (1u << 20));           // 2 MB
    float* wv           = (float*)(ws + 3u * (1u << 20));      // 4 KB
    int*   row_start    = (int*)  (ws + 3u * (1u << 20) + 4096);
    float* s_e          = (float*)(ws + 3u * (1u << 20) + 8192); // 512 KB

    prep_kernel<<<145, 256, 0, stream>>>(W_node, W_edge, w_attn, adj_mat,
                                         W_T, wv, row_start);
    gemm_g_kernel<<<dim3(8, 16), 256, 0, stream>>>(h_in, W_T, g);
    edge_scores_kernel<<<64, 256, 0, stream>>>(edge_attr, wv, s_e);
    attn_kernel<<<1024, 256, 0, stream>>>(g, adj_mat, s_e, row_start, w_attn, out);
}

// Round 3
// 107.259 us; speedup vs baseline: 1.0924x; 1.0924x over previous
//
#include <hip/hip_runtime.h>
#include <hip/hip_bf16.h>
#include <stdint.h>

#define BB 16
#define NN 64
#define DEG 16
#define IN_F 1024
#define EDGE_F 128
#define OUT_FT 512
#define HH 8
#define FF 64
#define EE (NN*DEG)
#define SLOPE 0.2f

typedef short s16x8 __attribute__((ext_vector_type(8)));
typedef float f32x4 __attribute__((ext_vector_type(4)));

__device__ __forceinline__ unsigned short f2bf(float x) {
    union { float f; uint32_t u; } v; v.f = x;
    uint32_t u = v.u;
    return (unsigned short)((u + 0x7FFFu + ((u >> 16) & 1u)) >> 16);  // RNE
}

// ---------------------------------------------------------------------------
// prep: blocks 0..127 : W_node[1024][512] -> W_T bf16 [512][1024] (transpose)
//       blocks 128..143: row_start scans
//       block  144    : wv[c][h] = W_edge[c, h*64:+64] . w_e
// ---------------------------------------------------------------------------
__global__ __launch_bounds__(256)
void prep_kernel(const float* __restrict__ W_node,
                 const float* __restrict__ W_edge,
                 const float* __restrict__ w_attn,
                 const float* __restrict__ adj,
                 unsigned short* __restrict__ W_T,
                 float* __restrict__ wv,
                 int* __restrict__ row_start)
{
    int bx = blockIdx.x;
    int tid = threadIdx.x;

    if (bx < 128) {
        __shared__ float tile[64][65];
        int tn = bx & 7, tk = bx >> 3;
        int k0 = tk * 64, n0 = tn * 64;
        #pragma unroll
        for (int j = 0; j < 16; ++j) {
            int lin = j * 256 + tid;
            int r = lin >> 6, c = lin & 63;
            tile[r][c] = W_node[(size_t)(k0 + r) * 512 + n0 + c];
        }
        __syncthreads();
        #pragma unroll
        for (int j = 0; j < 16; ++j) {
            int lin = j * 256 + tid;
            int nr = lin >> 6, kc = lin & 63;
            W_T[(size_t)(n0 + nr) * 1024 + k0 + kc] = f2bf(tile[kc][nr]);
        }
    } else if (bx < 144) {
        int b = bx - 128;
        if (tid < 64) {
            const float* row = adj + (size_t)b * 4096 + (size_t)tid * 64;
            int cnt = 0;
            #pragma unroll 8
            for (int j = 0; j < 64; ++j) cnt += (row[j] > 0.5f) ? 1 : 0;
            int inc = cnt;
            #pragma unroll
            for (int d = 1; d < 64; d <<= 1) {
                int u = __shfl_up(inc, d, 64);
                if (tid >= d) inc += u;
            }
            row_start[b * 64 + tid] = inc - cnt;
        }
    } else {
        int c = tid & 127;
        int half = tid >> 7;
        const float* we = w_attn + 2 * FF;
        #pragma unroll
        for (int hh = 0; hh < 4; ++hh) {
            int h = half * 4 + hh;
            float s = 0.f;
            const float* row = W_edge + (size_t)c * 512 + h * 64;
            #pragma unroll 8
            for (int f = 0; f < 64; ++f) s += row[f] * we[f];
            wv[c * 8 + h] = s;
        }
    }
}

// ---------------------------------------------------------------------------
// main: blocks 0..127 : g = h @ W_node (round-1 proven GEMM, fp32 g out)
//                       + fused s_i/s_j epilogue (register shfl reduction)
//       blocks 128..191: s_e[e][h] = edge_attr[e,:] . wv[:,h] (fp32)
// ---------------------------------------------------------------------------
__global__ __launch_bounds__(256)
void main_kernel(const float* __restrict__ hmat,            // [1024][1024]
                 const unsigned short* __restrict__ W_T,    // [512][1024] bf16
                 const float* __restrict__ edge_attr,       // [16384][128]
                 const float* __restrict__ wv,              // [128][8]
                 const float* __restrict__ w_attn,          // [192]
                 float* __restrict__ g,                     // [1024][512] fp32
                 float* __restrict__ s_e,                   // [16384][8]
                 float* __restrict__ s_i,                   // [1024][8]
                 float* __restrict__ s_j)                   // [1024][8]
{
    __shared__ __align__(16) unsigned short As[64][40];   // +8 pad (round-1)
    __shared__ __align__(16) unsigned short Bs[64][40];
    __shared__ float wvs[1024];

    int bx = blockIdx.x;
    int tid = threadIdx.x;

    if (bx < 128) {
        int head = bx & 7, mt = bx >> 3;
        int n0 = head * 64, m0 = mt * 64;
        int wave = tid >> 6, lane = tid & 63;
        int l15 = lane & 15, quad = lane >> 4;
        int wv16 = wave * 16;

        int ldr = tid >> 2;           // 0..63
        int ldc8 = (tid & 3) * 8;     // 0,8,16,24

        f32x4 acc[4];
        #pragma unroll
        for (int i = 0; i < 4; ++i) acc[i] = (f32x4){0.f, 0.f, 0.f, 0.f};

        for (int k0 = 0; k0 < 1024; k0 += 32) {
            const float* ap = hmat + (size_t)(m0 + ldr) * 1024 + k0 + ldc8;
            float4 a0 = *(const float4*)ap;
            float4 a1 = *(const float4*)(ap + 4);
            s16x8 av;
            av[0] = (short)f2bf(a0.x); av[1] = (short)f2bf(a0.y);
            av[2] = (short)f2bf(a0.z); av[3] = (short)f2bf(a0.w);
            av[4] = (short)f2bf(a1.x); av[5] = (short)f2bf(a1.y);
            av[6] = (short)f2bf(a1.z); av[7] = (short)f2bf(a1.w);
            *(s16x8*)&As[ldr][ldc8] = av;
            *(int4*)&Bs[ldr][ldc8] =
                *(const int4*)(W_T + (size_t)(n0 + ldr) * 1024 + k0 + ldc8);
            __syncthreads();

            s16x8 af = *(const s16x8*)&As[wv16 + l15][quad * 8];
            #pragma unroll
            for (int nt = 0; nt < 4; ++nt) {
                s16x8 bf = *(const s16x8*)&Bs[nt * 16 + l15][quad * 8];
                acc[nt] = __builtin_amdgcn_mfma_f32_16x16x32_bf16(af, bf, acc[nt], 0, 0, 0);
            }
            __syncthreads();
        }

        // g write (fp32, round-1 exact) + fused s_i/s_j row dots
        float wi[4], wj[4];
        #pragma unroll
        for (int nt = 0; nt < 4; ++nt) {
            wi[nt] = w_attn[nt * 16 + l15];
            wj[nt] = w_attn[64 + nt * 16 + l15];
        }
        float pi[4], pj[4];
        #pragma unroll
        for (int reg = 0; reg < 4; ++reg) { pi[reg] = 0.f; pj[reg] = 0.f; }

        #pragma unroll
        for (int nt = 0; nt < 4; ++nt) {
            #pragma unroll
            for (int reg = 0; reg < 4; ++reg) {
                int gm = m0 + wv16 + quad * 4 + reg;
                int gn = n0 + nt * 16 + l15;
                g[(size_t)gm * 512 + gn] = acc[nt][reg];
                pi[reg] += acc[nt][reg] * wi[nt];
                pj[reg] += acc[nt][reg] * wj[nt];
            }
        }
        #pragma unroll
        for (int mask = 1; mask < 16; mask <<= 1) {
            #pragma unroll
            for (int reg = 0; reg < 4; ++reg) {
                pi[reg] += __shfl_xor(pi[reg], mask);
                pj[reg] += __shfl_xor(pj[reg], mask);
            }
        }
        if (l15 == 0) {
            #pragma unroll
            for (int reg = 0; reg < 4; ++reg) {
                int r = m0 + wv16 + quad * 4 + reg;
                s_i[(size_t)r * 8 + head] = pi[reg];
                s_j[(size_t)r * 8 + head] = pj[reg];
            }
        }
    } else {
        // ---- edge scores (fp32 exact logits) ----
        ((float4*)wvs)[tid] = ((const float4*)wv)[tid];
        __syncthreads();
        int e = (bx - 128) * 256 + tid;
        const float4* erow = (const float4*)(edge_attr + (size_t)e * 128);
        f32x4 accl = {0.f, 0.f, 0.f, 0.f};
        f32x4 acch = {0.f, 0.f, 0.f, 0.f};
        for (int c4 = 0; c4 < 32; ++c4) {
            float4 v = erow[c4];
            #pragma unroll
            for (int u = 0; u < 4; ++u) {
                int c = c4 * 4 + u;
                f32x4 w0 = *(const f32x4*)&wvs[c * 8];
                f32x4 w1 = *(const f32x4*)&wvs[c * 8 + 4];
                float x = (u == 0) ? v.x : (u == 1) ? v.y : (u == 2) ? v.z : v.w;
                accl += x * w0;
                acch += x * w1;
            }
        }
        *(f32x4*)(s_e + (size_t)e * 8)     = accl;
        *(f32x4*)(s_e + (size_t)e * 8 + 4) = acch;
    }
}

// ---------------------------------------------------------------------------
// attn: one block per (b,i). Parallel fp32 staging, precomputed s_i/s_j/s_e.
// ---------------------------------------------------------------------------
__global__ __launch_bounds__(256)
void attn_kernel(const float* __restrict__ g,          // [1024][512] fp32
                 const float* __restrict__ adj,        // [16][64][64]
                 const float* __restrict__ s_e,        // [16384][8]
                 const float* __restrict__ s_i,        // [1024][8]
                 const float* __restrict__ s_j,        // [1024][8]
                 const int*   __restrict__ row_start,  // [1024]
                 float* __restrict__ out)              // [1024][512]
{
    __shared__ __align__(16) float gs[16][516];   // pad 4 floats (stride 2064 B)
    __shared__ float se_s[16][8];
    __shared__ float sj_s[16][8];
    __shared__ float a_s[16][8];
    __shared__ float si_s[8];
    __shared__ int nbr[16];
    __shared__ int m_nb_s;

    int bi = blockIdx.x;
    int b = bi >> 6, i = bi & 63;
    int tid = threadIdx.x;

    if (tid < 64) {
        float av = adj[(size_t)b * 4096 + (size_t)i * 64 + tid];
        unsigned long long m = __ballot(av > 0.5f);
        if (av > 0.5f) {
            int before = __popcll(m & ((1ull << tid) - 1ull));
            if (before < 16) nbr[before] = tid;
        }
        if (tid == 0) {
            int c = __popcll(m);
            m_nb_s = (c > 16) ? 16 : c;
        }
    }
    __syncthreads();

    int m_nb = m_nb_s;
    int rs = row_start[bi];

    // parallel staging: 16 threads per neighbor row, 8 x float4 each
    int slot = tid >> 4, l16 = tid & 15;
    if (slot < m_nb) {
        const float4* src4 = (const float4*)(g + (size_t)(b * 64 + nbr[slot]) * 512);
        #pragma unroll
        for (int j = 0; j < 8; ++j) {
            int q = j * 16 + l16;                 // 0..127 float4s
            *(float4*)&gs[slot][q * 4] = src4[q];
        }
    }
    if (tid < 128) {
        int k = tid >> 3, h = tid & 7;
        if (k < m_nb) {
            se_s[k][h] = s_e[(size_t)(b * 1024 + rs + k) * 8 + h];
            sj_s[k][h] = s_j[(size_t)(b * 64 + nbr[k]) * 8 + h];
        }
    } else if (tid < 136) {
        si_s[tid - 128] = s_i[(size_t)bi * 8 + (tid - 128)];
    }
    __syncthreads();

    // scores (leaky relu)
    if (tid < 128) {
        int k = tid >> 3, h = tid & 7;
        if (k < m_nb) {
            float v = si_s[h] + sj_s[k][h] + se_s[k][h];
            a_s[k][h] = (v >= 0.f) ? v : SLOPE * v;
        }
    }
    __syncthreads();

    // softmax per head
    if (tid < 8) {
        int h = tid;
        float mx = -1e30f;
        for (int k = 0; k < m_nb; ++k) mx = fmaxf(mx, a_s[k][h]);
        float ssum = 0.f;
        for (int k = 0; k < m_nb; ++k) {
            float e = __expf(a_s[k][h] - mx);
            a_s[k][h] = e;
            ssum += e;
        }
        float inv = 1.f / ssum;
        for (int k = 0; k < m_nb; ++k) a_s[k][h] *= inv;
    }
    __syncthreads();

    // aggregate: 2 output cols per thread
    int c0 = tid * 2;
    int h = tid >> 5;
    float a0 = 0.f, a1 = 0.f;
    for (int k = 0; k < m_nb; ++k) {
        float ak = a_s[k][h];
        a0 += ak * gs[k][c0];
        a1 += ak * gs[k][c0 + 1];
    }
    out[(size_t)bi * 512 + c0]     = a0;
    out[(size_t)bi * 512 + c0 + 1] = a1;
}

// ---------------------------------------------------------------------------
extern "C" void kernel_launch(void* const* d_in, const int* in_sizes, int n_in,
                              void* d_out, int out_size, void* d_ws, size_t ws_size,
                              hipStream_t stream) {
    const float* h_in      = (const float*)d_in[0];   // (16,64,1024)
    const float* adj_mat   = (const float*)d_in[1];   // (16,64,64)
    const float* edge_attr = (const float*)d_in[2];   // (16,1024,128)
    const float* W_node    = (const float*)d_in[3];   // (1024,512)
    const float* W_edge    = (const float*)d_in[4];   // (128,512)
    const float* w_attn    = (const float*)d_in[5];   // (192,)
    float* out = (float*)d_out;                       // (16,64,512) fp32

    char* ws = (char*)d_ws;
    unsigned short* W_T = (unsigned short*)(ws + 0x000000);   // 1 MB
    float* g            = (float*)(ws + 0x100000);            // 2 MB
    float* s_e          = (float*)(ws + 0x300000);            // 512 KB
    float* s_i          = (float*)(ws + 0x380000);            // 32 KB
    float* s_j          = (float*)(ws + 0x388000);            // 32 KB
    float* wv           = (float*)(ws + 0x390000);            // 4 KB
    int*   row_start    = (int*)  (ws + 0x391000);            // 4 KB

    prep_kernel<<<145, 256, 0, stream>>>(W_node, W_edge, w_attn, adj_mat,
                                         W_T, wv, row_start);
    main_kernel<<<192, 256, 0, stream>>>(h_in, W_T, edge_attr, wv, w_attn,
                                         g, s_e, s_i, s_j);
    attn_kernel<<<1024, 256, 0, stream>>>(g, adj_mat, s_e, s_i, s_j,
                                          row_start, out);
}

// Round 4
// 102.201 us; speedup vs baseline: 1.1465x; 1.0495x over previous
//
#include <hip/hip_runtime.h>
#include <hip/hip_bf16.h>
#include <stdint.h>

#define BB 16
#define NN 64
#define DEG 16
#define IN_F 1024
#define EDGE_F 128
#define OUT_FT 512
#define HH 8
#define FF 64
#define EE (NN*DEG)
#define SLOPE 0.2f

typedef short s16x8 __attribute__((ext_vector_type(8)));
typedef float f32x4 __attribute__((ext_vector_type(4)));

__device__ __forceinline__ unsigned short f2bf(float x) {
    union { float f; uint32_t u; } v; v.f = x;
    uint32_t u = v.u;
    return (unsigned short)((u + 0x7FFFu + ((u >> 16) & 1u)) >> 16);  // RNE
}

// ---------------------------------------------------------------------------
// prep: blocks 0..127 : W_node[1024][512] -> W_T bf16 [512][1024] (transpose)
//       blocks 128..143: row_start scans
//       block  144    : wv[c][h] = W_edge[c, h*64:+64] . w_e
// ---------------------------------------------------------------------------
__global__ __launch_bounds__(256)
void prep_kernel(const float* __restrict__ W_node,
                 const float* __restrict__ W_edge,
                 const float* __restrict__ w_attn,
                 const float* __restrict__ adj,
                 unsigned short* __restrict__ W_T,
                 float* __restrict__ wv,
                 int* __restrict__ row_start)
{
    int bx = blockIdx.x;
    int tid = threadIdx.x;

    if (bx < 128) {
        __shared__ float tile[64][65];
        int tn = bx & 7, tk = bx >> 3;
        int k0 = tk * 64, n0 = tn * 64;
        #pragma unroll
        for (int j = 0; j < 16; ++j) {
            int lin = j * 256 + tid;
            int r = lin >> 6, c = lin & 63;
            tile[r][c] = W_node[(size_t)(k0 + r) * 512 + n0 + c];
        }
        __syncthreads();
        #pragma unroll
        for (int j = 0; j < 16; ++j) {
            int lin = j * 256 + tid;
            int nr = lin >> 6, kc = lin & 63;
            W_T[(size_t)(n0 + nr) * 1024 + k0 + kc] = f2bf(tile[kc][nr]);
        }
    } else if (bx < 144) {
        int b = bx - 128;
        if (tid < 64) {
            const float* row = adj + (size_t)b * 4096 + (size_t)tid * 64;
            int cnt = 0;
            #pragma unroll 8
            for (int j = 0; j < 64; ++j) cnt += (row[j] > 0.5f) ? 1 : 0;
            int inc = cnt;
            #pragma unroll
            for (int d = 1; d < 64; d <<= 1) {
                int u = __shfl_up(inc, d, 64);
                if (tid >= d) inc += u;
            }
            row_start[b * 64 + tid] = inc - cnt;
        }
    } else {
        int c = tid & 127;
        int half = tid >> 7;
        const float* we = w_attn + 2 * FF;
        #pragma unroll
        for (int hh = 0; hh < 4; ++hh) {
            int h = half * 4 + hh;
            float s = 0.f;
            const float* row = W_edge + (size_t)c * 512 + h * 64;
            #pragma unroll 8
            for (int f = 0; f < 64; ++f) s += row[f] * we[f];
            wv[c * 8 + h] = s;
        }
    }
}

// ---------------------------------------------------------------------------
// main: blocks 0..127 : g = h @ W_node (double-buffered register-prefetch
//                       K-loop; bitwise-identical MFMA order to round 3)
//                       + fused s_i/s_j epilogue
//       blocks 128..191: s_e[e][h] = edge_attr[e,:] . wv[:,h] (fp32)
// ---------------------------------------------------------------------------
__global__ __launch_bounds__(256)
void main_kernel(const float* __restrict__ hmat,            // [1024][1024]
                 const unsigned short* __restrict__ W_T,    // [512][1024] bf16
                 const float* __restrict__ edge_attr,       // [16384][128]
                 const float* __restrict__ wv,              // [128][8]
                 const float* __restrict__ w_attn,          // [192]
                 float* __restrict__ g,                     // [1024][512] fp32
                 float* __restrict__ s_e,                   // [16384][8]
                 float* __restrict__ s_i,                   // [1024][8]
                 float* __restrict__ s_j)                   // [1024][8]
{
    __shared__ __align__(16) unsigned short As[2][64][40];   // double-buffered
    __shared__ __align__(16) unsigned short Bs[2][64][40];
    __shared__ float wvs[1024];

    int bx = blockIdx.x;
    int tid = threadIdx.x;

    if (bx < 128) {
        int head = bx & 7, mt = bx >> 3;
        int n0 = head * 64, m0 = mt * 64;
        int wave = tid >> 6, lane = tid & 63;
        int l15 = lane & 15, quad = lane >> 4;
        int wv16 = wave * 16;

        int ldr = tid >> 2;           // 0..63
        int ldc8 = (tid & 3) * 8;     // 0,8,16,24

        const float* apBase = hmat + (size_t)(m0 + ldr) * 1024 + ldc8;
        const unsigned short* bpBase = W_T + (size_t)(n0 + ldr) * 1024 + ldc8;

        f32x4 acc[4];
        #pragma unroll
        for (int i = 0; i < 4; ++i) acc[i] = (f32x4){0.f, 0.f, 0.f, 0.f};

        // preload iteration 0
        float4 a0 = *(const float4*)(apBase);
        float4 a1 = *(const float4*)(apBase + 4);
        int4   bv = *(const int4*)(bpBase);
        {
            s16x8 av;
            av[0] = (short)f2bf(a0.x); av[1] = (short)f2bf(a0.y);
            av[2] = (short)f2bf(a0.z); av[3] = (short)f2bf(a0.w);
            av[4] = (short)f2bf(a1.x); av[5] = (short)f2bf(a1.y);
            av[6] = (short)f2bf(a1.z); av[7] = (short)f2bf(a1.w);
            *(s16x8*)&As[0][ldr][ldc8] = av;
            *(int4*)&Bs[0][ldr][ldc8] = bv;
        }

        for (int it = 0; it < 32; ++it) {
            __syncthreads();                 // LDS[it&1] ready
            if (it + 1 < 32) {               // prefetch next tile into regs
                const float* ap = apBase + (it + 1) * 32;
                a0 = *(const float4*)ap;
                a1 = *(const float4*)(ap + 4);
                bv = *(const int4*)(bpBase + (it + 1) * 32);
            }
            int cur = it & 1;
            s16x8 af = *(const s16x8*)&As[cur][wv16 + l15][quad * 8];
            #pragma unroll
            for (int nt = 0; nt < 4; ++nt) {
                s16x8 bf = *(const s16x8*)&Bs[cur][nt * 16 + l15][quad * 8];
                acc[nt] = __builtin_amdgcn_mfma_f32_16x16x32_bf16(af, bf, acc[nt], 0, 0, 0);
            }
            if (it + 1 < 32) {               // stage next tile (other buffer)
                int nxt = cur ^ 1;
                s16x8 av;
                av[0] = (short)f2bf(a0.x); av[1] = (short)f2bf(a0.y);
                av[2] = (short)f2bf(a0.z); av[3] = (short)f2bf(a0.w);
                av[4] = (short)f2bf(a1.x); av[5] = (short)f2bf(a1.y);
                av[6] = (short)f2bf(a1.z); av[7] = (short)f2bf(a1.w);
                *(s16x8*)&As[nxt][ldr][ldc8] = av;
                *(int4*)&Bs[nxt][ldr][ldc8] = bv;
            }
        }

        // g write (fp32) + fused s_i/s_j row dots (register shfl reduction)
        float wi[4], wj[4];
        #pragma unroll
        for (int nt = 0; nt < 4; ++nt) {
            wi[nt] = w_attn[nt * 16 + l15];
            wj[nt] = w_attn[64 + nt * 16 + l15];
        }
        float pi[4], pj[4];
        #pragma unroll
        for (int reg = 0; reg < 4; ++reg) { pi[reg] = 0.f; pj[reg] = 0.f; }

        #pragma unroll
        for (int nt = 0; nt < 4; ++nt) {
            #pragma unroll
            for (int reg = 0; reg < 4; ++reg) {
                int gm = m0 + wv16 + quad * 4 + reg;
                int gn = n0 + nt * 16 + l15;
                g[(size_t)gm * 512 + gn] = acc[nt][reg];
                pi[reg] += acc[nt][reg] * wi[nt];
                pj[reg] += acc[nt][reg] * wj[nt];
            }
        }
        #pragma unroll
        for (int mask = 1; mask < 16; mask <<= 1) {
            #pragma unroll
            for (int reg = 0; reg < 4; ++reg) {
                pi[reg] += __shfl_xor(pi[reg], mask);
                pj[reg] += __shfl_xor(pj[reg], mask);
            }
        }
        if (l15 == 0) {
            #pragma unroll
            for (int reg = 0; reg < 4; ++reg) {
                int r = m0 + wv16 + quad * 4 + reg;
                s_i[(size_t)r * 8 + head] = pi[reg];
                s_j[(size_t)r * 8 + head] = pj[reg];
            }
        }
    } else {
        // ---- edge scores (fp32 exact logits) ----
        ((float4*)wvs)[tid] = ((const float4*)wv)[tid];
        __syncthreads();
        int e = (bx - 128) * 256 + tid;
        const float4* erow = (const float4*)(edge_attr + (size_t)e * 128);
        f32x4 accl = {0.f, 0.f, 0.f, 0.f};
        f32x4 acch = {0.f, 0.f, 0.f, 0.f};
        for (int c4 = 0; c4 < 32; ++c4) {
            float4 v = erow[c4];
            #pragma unroll
            for (int u = 0; u < 4; ++u) {
                int c = c4 * 4 + u;
                f32x4 w0 = *(const f32x4*)&wvs[c * 8];
                f32x4 w1 = *(const f32x4*)&wvs[c * 8 + 4];
                float x = (u == 0) ? v.x : (u == 1) ? v.y : (u == 2) ? v.z : v.w;
                accl += x * w0;
                acch += x * w1;
            }
        }
        *(f32x4*)(s_e + (size_t)e * 8)     = accl;
        *(f32x4*)(s_e + (size_t)e * 8 + 4) = acch;
    }
}

// ---------------------------------------------------------------------------
// attn: one block per (b,i). Parallel fp32 staging, precomputed s_i/s_j/s_e.
// ---------------------------------------------------------------------------
__global__ __launch_bounds__(256)
void attn_kernel(const float* __restrict__ g,          // [1024][512] fp32
                 const float* __restrict__ adj,        // [16][64][64]
                 const float* __restrict__ s_e,        // [16384][8]
                 const float* __restrict__ s_i,        // [1024][8]
                 const float* __restrict__ s_j,        // [1024][8]
                 const int*   __restrict__ row_start,  // [1024]
                 float* __restrict__ out)              // [1024][512]
{
    __shared__ __align__(16) float gs[16][516];
    __shared__ float se_s[16][8];
    __shared__ float sj_s[16][8];
    __shared__ float a_s[16][8];
    __shared__ float si_s[8];
    __shared__ int nbr[16];
    __shared__ int m_nb_s;

    int bi = blockIdx.x;
    int b = bi >> 6, i = bi & 63;
    int tid = threadIdx.x;

    if (tid < 64) {
        float av = adj[(size_t)b * 4096 + (size_t)i * 64 + tid];
        unsigned long long m = __ballot(av > 0.5f);
        if (av > 0.5f) {
            int before = __popcll(m & ((1ull << tid) - 1ull));
            if (before < 16) nbr[before] = tid;
        }
        if (tid == 0) {
            int c = __popcll(m);
            m_nb_s = (c > 16) ? 16 : c;
        }
    }
    __syncthreads();

    int m_nb = m_nb_s;
    int rs = row_start[bi];

    // parallel staging: 16 threads per neighbor row, 8 x float4 each
    int slot = tid >> 4, l16 = tid & 15;
    if (slot < m_nb) {
        const float4* src4 = (const float4*)(g + (size_t)(b * 64 + nbr[slot]) * 512);
        #pragma unroll
        for (int j = 0; j < 8; ++j) {
            int q = j * 16 + l16;
            *(float4*)&gs[slot][q * 4] = src4[q];
        }
    }
    if (tid < 128) {
        int k = tid >> 3, h = tid & 7;
        if (k < m_nb) {
            se_s[k][h] = s_e[(size_t)(b * 1024 + rs + k) * 8 + h];
            sj_s[k][h] = s_j[(size_t)(b * 64 + nbr[k]) * 8 + h];
        }
    } else if (tid < 136) {
        si_s[tid - 128] = s_i[(size_t)bi * 8 + (tid - 128)];
    }
    __syncthreads();

    // fused scores + softmax per head (8 lanes)
    if (tid < 8) {
        int h = tid;
        float si = si_s[h];
        float sc[16];
        float mx = -1e30f;
        for (int k = 0; k < m_nb; ++k) {
            float v = si + sj_s[k][h] + se_s[k][h];
            v = (v >= 0.f) ? v : SLOPE * v;
            sc[k] = v;
            mx = fmaxf(mx, v);
        }
        float ssum = 0.f;
        for (int k = 0; k < m_nb; ++k) {
            float e = __expf(sc[k] - mx);
            a_s[k][h] = e;
            ssum += e;
        }
        float inv = 1.f / ssum;
        for (int k = 0; k < m_nb; ++k) a_s[k][h] *= inv;
    }
    __syncthreads();

    // aggregate: 2 output cols per thread
    int c0 = tid * 2;
    int h = tid >> 5;
    float a0 = 0.f, a1 = 0.f;
    for (int k = 0; k < m_nb; ++k) {
        float ak = a_s[k][h];
        a0 += ak * gs[k][c0];
        a1 += ak * gs[k][c0 + 1];
    }
    out[(size_t)bi * 512 + c0]     = a0;
    out[(size_t)bi * 512 + c0 + 1] = a1;
}

// ---------------------------------------------------------------------------
extern "C" void kernel_launch(void* const* d_in, const int* in_sizes, int n_in,
                              void* d_out, int out_size, void* d_ws, size_t ws_size,
                              hipStream_t stream) {
    const float* h_in      = (const float*)d_in[0];   // (16,64,1024)
    const float* adj_mat   = (const float*)d_in[1];   // (16,64,64)
    const float* edge_attr = (const float*)d_in[2];   // (16,1024,128)
    const float* W_node    = (const float*)d_in[3];   // (1024,512)
    const float* W_edge    = (const float*)d_in[4];   // (128,512)
    const float* w_attn    = (const float*)d_in[5];   // (192,)
    float* out = (float*)d_out;                       // (16,64,512) fp32

    char* ws = (char*)d_ws;
    unsigned short* W_T = (unsigned short*)(ws + 0x000000);   // 1 MB
    float* g            = (float*)(ws + 0x100000);            // 2 MB
    float* s_e          = (float*)(ws + 0x300000);            // 512 KB
    float* s_i          = (float*)(ws + 0x380000);            // 32 KB
    float* s_j          = (float*)(ws + 0x388000);            // 32 KB
    float* wv           = (float*)(ws + 0x390000);            // 4 KB
    int*   row_start    = (int*)  (ws + 0x391000);            // 4 KB

    prep_kernel<<<145, 256, 0, stream>>>(W_node, W_edge, w_attn, adj_mat,
                                         W_T, wv, row_start);
    main_kernel<<<192, 256, 0, stream>>>(h_in, W_T, edge_attr, wv, w_attn,
                                         g, s_e, s_i, s_j);
    attn_kernel<<<1024, 256, 0, stream>>>(g, adj_mat, s_e, s_i, s_j,
                                          row_start, out);
}